// Round 2
// baseline (129.181 us; speedup 1.0000x reference)
//
#include <hip/hip_runtime.h>

// SASA plain 3-kernel pipeline, R7 (resubmit — prior bench was an infra flake):
// bf16 LDS in phase-2 + nt-fastest p1 order.
// B=2, CIN=192, HW=3136, 6 heads x d=32, 7x7 window.
// Cost model (calibrated R1-R6): dur_us = kernels + ~95us harness ws-poison (fixed,
// 2x256MiB fills at 77% HBM peak). Controllable kernel time ~16us.
// R7 changes:
//  (a) p2 stages K/V in LDS as bf16 (was fp32): LDS-read traffic halves in the
//      LDS-bound inner loops (2x ds_read_b128 per kk instead of 4); unpack moves
//      to VALU (+16 instr/kk). Row stride 40 shorts (80B) -> balanced 8-deep
//      banks for staging writes and windowed reads, all uint4 ops 16B-aligned.
//      LDS 53.3KB -> 31.4KB (~5 blocks/CU). Math bit-identical to R6.
//  (b) p1 block index nt-fastest (t%9): co-resident blocks share one 64-px
//      A-strip; x streamed from HBM once, weights stay L2-resident.
//
// ws layout (bytes):
//   QKV  [6272][576] bf16 @ 0        q ch 0-191 | k 192-383 | v 384-575
//   OACT [6272][192] bf16 @ 7225344  attention out = proj B-operand

#define HW    3136
#define WIMG  56
#define CIN   192
#define QKVLD 576
#define SMEM_P1 51200
#define SMEM_P2 31360
// p2 LDS row stride in shorts (32 ch + 8 pad -> 80B, 16B aligned, bank-balanced)
#define KVSTR 40

using short8 = __attribute__((ext_vector_type(8))) short;
using f32x4  = __attribute__((ext_vector_type(4))) float;

__device__ __forceinline__ unsigned short f2bf(float f) {
    union { float f; unsigned u; } v; v.f = f;
    unsigned r = v.u + 0x7fffu + ((v.u >> 16) & 1u);
    return (unsigned short)(r >> 16);
}
__device__ __forceinline__ unsigned pack2(float a, float b) {
    return (unsigned)f2bf(a) | ((unsigned)f2bf(b) << 16);
}
__device__ __forceinline__ float bflo(unsigned u) {
    union { unsigned u; float f; } v; v.u = u << 16; return v.f;
}
__device__ __forceinline__ float bfhi(unsigned u) {
    union { unsigned u; float f; } v; v.u = u & 0xffff0000u; return v.f;
}

// ======================= Phase 1: QKV GEMM tile =============================
// t in [0,882): nt = t%9 (64 of 576 out ch, FASTEST), mt = t/9 (64-pixel strip).
// A: transpose x[b][c][p] fp32 -> As[p][c] bf16 in staging. B: W rows -> bf16.
__global__ __launch_bounds__(256) void k_p1(
    const float* __restrict__ x, const float* __restrict__ wq,
    const float* __restrict__ wk, const float* __restrict__ wv,
    unsigned short* __restrict__ qkv)
{
    extern __shared__ char smem[];
    unsigned short* As  = (unsigned short*)smem;     // 64 x 200 ushorts
    unsigned short* Bs  = As + 64 * 200;
    unsigned*       Asw = (unsigned*)smem;           // dword view, row stride 100
    unsigned*       Bsw = (unsigned*)(smem + 25600);

    const int tid = threadIdx.x;
    const int lane = tid & 63, wave = tid >> 6;
    const int l15  = lane & 15, quad = lane >> 4;
    const int wm   = (wave & 1) * 32, wn = (wave >> 1) * 32;

    const int t = blockIdx.x;
    const int nt = t % 9, mt = t / 9;               // R7: nt fastest
    const int m0 = mt * 64, n0 = nt * 64;
    const float* Wp = (nt < 3) ? (wq + (size_t)n0 * CIN)
                    : (nt < 6) ? (wk + (size_t)(n0 - 192) * CIN)
                               : (wv + (size_t)(n0 - 384) * CIN);

    #pragma unroll
    for (int i = 0; i < 6; ++i) {
        int u = tid + 256 * i;
        int pq = u & 15, c2 = u >> 4;            // pq: p-quad 0..15, c2: 0..95
        int pp = m0 + pq * 4;
        int bb = (pp >= HW) ? 1 : 0;
        const float* src = x + ((size_t)(bb * CIN + c2 * 2)) * HW + (pp - bb * HW);
        float4 f0 = *(const float4*)src;          // c = c2*2,   p..p+3
        float4 f1 = *(const float4*)(src + HW);   // c = c2*2+1, p..p+3
        Asw[(pq * 4 + 0) * 100 + c2] = pack2(f0.x, f1.x);
        Asw[(pq * 4 + 1) * 100 + c2] = pack2(f0.y, f1.y);
        Asw[(pq * 4 + 2) * 100 + c2] = pack2(f0.z, f1.z);
        Asw[(pq * 4 + 3) * 100 + c2] = pack2(f0.w, f1.w);
    }
    {
        int o = tid >> 2, c4 = tid & 3;
        #pragma unroll
        for (int i = 0; i < 12; ++i) {
            int cq = c4 + 4 * i;                 // 0..47
            float4 w = *(const float4*)(Wp + (size_t)o * CIN + cq * 4);
            uint2 d; d.x = pack2(w.x, w.y); d.y = pack2(w.z, w.w);
            *(uint2*)(Bsw + o * 100 + cq * 2) = d;
        }
    }
    __syncthreads();

    f32x4 acc[2][2] = {};
    const unsigned short* pa0 = As + (wm + l15) * 200 + quad * 8;
    const unsigned short* pb0 = Bs + (wn + l15) * 200 + quad * 8;
    #pragma unroll
    for (int s = 0; s < 6; ++s) {
        short8 a0 = *(const short8*)(pa0 + s * 32);
        short8 a1 = *(const short8*)(pa0 + 16 * 200 + s * 32);
        short8 b0 = *(const short8*)(pb0 + s * 32);
        short8 b1 = *(const short8*)(pb0 + 16 * 200 + s * 32);
        acc[0][0] = __builtin_amdgcn_mfma_f32_16x16x32_bf16(a0, b0, acc[0][0], 0, 0, 0);
        acc[0][1] = __builtin_amdgcn_mfma_f32_16x16x32_bf16(a0, b1, acc[0][1], 0, 0, 0);
        acc[1][0] = __builtin_amdgcn_mfma_f32_16x16x32_bf16(a1, b0, acc[1][0], 0, 0, 0);
        acc[1][1] = __builtin_amdgcn_mfma_f32_16x16x32_bf16(a1, b1, acc[1][1], 0, 0, 0);
    }

    const int gm = m0 + wm + quad * 4;   // global pixel row
    const int gn = n0 + wn + l15;        // output channel (0..575)
    #pragma unroll
    for (int ti = 0; ti < 2; ++ti)
        #pragma unroll
        for (int tj = 0; tj < 2; ++tj)
            #pragma unroll
            for (int rr = 0; rr < 4; ++rr)
                qkv[(size_t)(gm + ti * 16 + rr) * QKVLD + (gn + tj * 16)] =
                    f2bf(acc[ti][tj][rr]);
}

// ======================= Phase 2: windowed attention ========================
// t in [0,588): 49 8x8-pixel tiles x 12 (b,h). 4 threads/pixel (d split 4x8).
// K and V staged as bf16 in LDS (R7); unpack to fp32 after the LDS read.
__global__ __launch_bounds__(256) void k_p2(
    const unsigned short* __restrict__ qkv, const float* __restrict__ pos,
    unsigned short* __restrict__ oact)
{
    extern __shared__ char smem[];
    unsigned short* kbuf = (unsigned short*)smem;   // [196 px][32 ch] stride 40
    unsigned short* vbuf = kbuf + 196 * KVSTR;

    const int tid = threadIdx.x;
    const int t = blockIdx.x;
    const int tz = t / 49, r49 = t - tz * 49;
    const int ty = r49 / 7, tx = r49 - ty * 7;
    const int bq = tz / 6, h = tz - bq * 6;
    const int y0 = ty * 8 - 3, x0 = tx * 8 - 3;

    // unified K+V staging: 1568 uint4 units = 196 px * (4 k + 4 v), raw bf16
    #pragma unroll
    for (int i = 0; i < 7; ++i) {
        int u = tid + 256 * i;
        if (u < 1568) {
            int pp = u >> 3, uu = u & 7;
            int part = uu >> 2, sub8 = uu & 3;       // part 0=k, 1=v
            int py = pp / 14, px = pp - py * 14;
            int gy = y0 + py, gx = x0 + px;
            uint4 rv = make_uint4(0u, 0u, 0u, 0u);
            if ((unsigned)gy < 56u && (unsigned)gx < 56u)
                rv = *(const uint4*)(qkv +
                    (size_t)(bq * HW + gy * WIMG + gx) * QKVLD +
                    192 + part * 192 + h * 32 + sub8 * 8);
            *(uint4*)((part ? vbuf : kbuf) + pp * KVSTR + sub8 * 8) = rv;
        }
    }
    __syncthreads();

    const int sub = tid & 3, pix = tid >> 2;
    const int py = pix >> 3, px = pix & 7;
    const int y = ty * 8 + py, xx = tx * 8 + px;
    const int p = y * WIMG + xx;

    uint4 qv = *(const uint4*)(qkv + (size_t)(bq * HW + p) * QKVLD + h * 32 + sub * 8);
    float q0=bflo(qv.x), q1=bfhi(qv.x), q2=bflo(qv.y), q3=bfhi(qv.y);
    float q4=bflo(qv.z), q5=bfhi(qv.z), q6=bflo(qv.w), q7=bfhi(qv.w);

    float posr[13];
    #pragma unroll
    for (int i = 0; i < 13; ++i) posr[i] = pos[i];

    float logits[49];
    #pragma unroll
    for (int kk = 0; kk < 49; ++kk) {
        const int ky = kk / 7, kx = kk % 7;
        const int pp = (py + ky) * 14 + (px + kx);
        uint4 kv = *(const uint4*)(kbuf + pp * KVSTR + sub * 8);
        float s = 0.f;
        s = fmaf(q0, bflo(kv.x), s); s = fmaf(q1, bfhi(kv.x), s);
        s = fmaf(q2, bflo(kv.y), s); s = fmaf(q3, bfhi(kv.y), s);
        s = fmaf(q4, bflo(kv.z), s); s = fmaf(q5, bfhi(kv.z), s);
        s = fmaf(q6, bflo(kv.w), s); s = fmaf(q7, bfhi(kv.w), s);
        s += __shfl_xor(s, 1);
        s += __shfl_xor(s, 2);
        logits[kk] = s + posr[ky + kx];
    }

    float m = logits[0];
    #pragma unroll
    for (int kk = 1; kk < 49; ++kk) m = fmaxf(m, logits[kk]);
    float sum = 0.f;
    #pragma unroll
    for (int kk = 0; kk < 49; ++kk) {
        logits[kk] = __expf(logits[kk] - m);
        sum += logits[kk];
    }
    const float inv = 1.f / sum;

    float a0=0,a1=0,a2=0,a3=0,a4=0,a5=0,a6=0,a7=0;
    #pragma unroll
    for (int kk = 0; kk < 49; ++kk) {
        const int ky = kk / 7, kx = kk % 7;
        const int pp = (py + ky) * 14 + (px + kx);
        uint4 vv = *(const uint4*)(vbuf + pp * KVSTR + sub * 8);
        const float pw = logits[kk] * inv;
        a0 = fmaf(pw, bflo(vv.x), a0); a1 = fmaf(pw, bfhi(vv.x), a1);
        a2 = fmaf(pw, bflo(vv.y), a2); a3 = fmaf(pw, bfhi(vv.y), a3);
        a4 = fmaf(pw, bflo(vv.z), a4); a5 = fmaf(pw, bfhi(vv.z), a5);
        a6 = fmaf(pw, bflo(vv.w), a6); a7 = fmaf(pw, bfhi(vv.w), a7);
    }

    ushort4 h0, h1;
    h0.x = f2bf(a0); h0.y = f2bf(a1); h0.z = f2bf(a2); h0.w = f2bf(a3);
    h1.x = f2bf(a4); h1.y = f2bf(a5); h1.z = f2bf(a6); h1.w = f2bf(a7);
    unsigned short* ob = oact + (size_t)(bq * HW + p) * CIN + h * 32 + sub * 8;
    *(ushort4*)ob       = h0;
    *(ushort4*)(ob + 4) = h1;
}

// ======================= Phase 3: projection tile ===========================
// t in [0,294): mt = t%3 (64 out ch), pt = t/3 (64-pixel strip).
__global__ __launch_bounds__(256) void k_p3(
    const float* __restrict__ wproj, const unsigned short* __restrict__ oact,
    float* __restrict__ out)
{
    extern __shared__ char smem[];
    unsigned short* As  = (unsigned short*)smem;
    unsigned short* Bs  = As + 64 * 200;
    unsigned*       Asw = (unsigned*)smem;

    const int tid = threadIdx.x;
    const int lane = tid & 63, wave = tid >> 6;
    const int l15  = lane & 15, quad = lane >> 4;
    const int wm   = (wave & 1) * 32, wn = (wave >> 1) * 32;

    const int t = blockIdx.x;
    const int mt = t % 3, pt = t / 3;
    {
        int o = tid >> 2, c4 = tid & 3;
        #pragma unroll
        for (int i = 0; i < 12; ++i) {
            int cq = c4 + 4 * i;
            float4 w = *(const float4*)(wproj + (size_t)(mt * 64 + o) * CIN + cq * 4);
            uint2 d; d.x = pack2(w.x, w.y); d.y = pack2(w.z, w.w);
            *(uint2*)(Asw + o * 100 + cq * 2) = d;
        }
    }
    {
        int rw = tid >> 2, s4 = tid & 3;
        #pragma unroll
        for (int i = 0; i < 6; ++i) {
            int seg = s4 + 4 * i;               // 0..23
            uint4 dv = *(const uint4*)(oact + (size_t)(pt * 64 + rw) * CIN + seg * 8);
            *(uint4*)(Bs + rw * 200 + seg * 8) = dv;
        }
    }
    __syncthreads();

    f32x4 acc[2][2] = {};
    const unsigned short* pa0 = As + (wm + l15) * 200 + quad * 8;
    const unsigned short* pb0 = Bs + (wn + l15) * 200 + quad * 8;
    #pragma unroll
    for (int s = 0; s < 6; ++s) {
        short8 a0 = *(const short8*)(pa0 + s * 32);
        short8 a1 = *(const short8*)(pa0 + 16 * 200 + s * 32);
        short8 b0 = *(const short8*)(pb0 + s * 32);
        short8 b1 = *(const short8*)(pb0 + 16 * 200 + s * 32);
        acc[0][0] = __builtin_amdgcn_mfma_f32_16x16x32_bf16(a0, b0, acc[0][0], 0, 0, 0);
        acc[0][1] = __builtin_amdgcn_mfma_f32_16x16x32_bf16(a0, b1, acc[0][1], 0, 0, 0);
        acc[1][0] = __builtin_amdgcn_mfma_f32_16x16x32_bf16(a1, b0, acc[1][0], 0, 0, 0);
        acc[1][1] = __builtin_amdgcn_mfma_f32_16x16x32_bf16(a1, b1, acc[1][1], 0, 0, 0);
    }

    const int bb = (pt * 64 >= HW) ? 1 : 0;
    const int pl = pt * 64 - bb * HW + wn + l15;      // col = pixel within batch
    const int go = mt * 64 + wm + quad * 4;           // row = output channel
    float* Yb = out + (size_t)bb * (CIN * HW);
    #pragma unroll
    for (int ti = 0; ti < 2; ++ti)
        #pragma unroll
        for (int tj = 0; tj < 2; ++tj)
            #pragma unroll
            for (int rr = 0; rr < 4; ++rr)
                Yb[(size_t)(go + ti * 16 + rr) * HW + pl + tj * 16] = acc[ti][tj][rr];
}

// ---------------------------------------------------------------------------
extern "C" void kernel_launch(void* const* d_in, const int* in_sizes, int n_in,
                              void* d_out, int out_size, void* d_ws, size_t ws_size,
                              hipStream_t stream)
{
    const float* x     = (const float*)d_in[0];
    const float* wq    = (const float*)d_in[1];
    const float* wk    = (const float*)d_in[2];
    const float* wv    = (const float*)d_in[3];
    const float* pos   = (const float*)d_in[4];
    const float* wproj = (const float*)d_in[5];

    char* ws = (char*)d_ws;
    unsigned short* qkvp  = (unsigned short*)ws;
    unsigned short* oactp = (unsigned short*)(ws + 7225344);
    float*          outp  = (float*)d_out;

    k_p1<<<dim3(882), dim3(256), SMEM_P1, stream>>>(x, wq, wk, wv, qkvp);
    k_p2<<<dim3(588), dim3(256), SMEM_P2, stream>>>(qkvp, pos, oactp);
    k_p3<<<dim3(294), dim3(256), SMEM_P1, stream>>>(wproj, oactp, outp);
}

// Round 3
// 113.818 us; speedup vs baseline: 1.1350x; 1.1350x over previous
//
#include <hip/hip_runtime.h>

// SASA plain 3-kernel pipeline, R8.
// B=2, CIN=192, HW=3136, 6 heads x d=32, 7x7 window.
// Cost model: dur_us = kernels + ~86us harness ws-poison (2x256MiB fills @43us,
// HBM-bound -> use fill time as container-health calibration).
// R8 changes vs R7:
//  (a) p1 back to mt-fastest (R6 order): nt-fastest mechanism weak (grid ~fully
//      co-resident), removed as an unproven variable after the noisy R7 round.
//  (b) p2 logit reduce via DPP quad_perm (VALU) instead of __shfl_xor
//      (ds_swizzle = LDS pipe). Removes 98 swizzle ops/wave from the bottleneck
//      LDS pipe; xor1/xor2 stay within a quad of 4 lanes. Bit-identical.
//  (c) p2 softmax 1/sum deferred to the 8 output accumulators (-41 VALU/thread).
//  (d) p2 Q + pos loads hoisted above LDS staging (latency overlaps stores).
// Kept from R7: bf16 K/V LDS (stride 40 shorts = 80B -> verified balanced banks:
// 8 word-accesses/bank for the windowed b128 reads, the theoretical minimum).
//
// ws layout (bytes):
//   QKV  [6272][576] bf16 @ 0        q ch 0-191 | k 192-383 | v 384-575
//   OACT [6272][192] bf16 @ 7225344  attention out = proj B-operand

#define HW    3136
#define WIMG  56
#define CIN   192
#define QKVLD 576
#define SMEM_P1 51200
#define SMEM_P2 31360
#define KVSTR 40

using short8 = __attribute__((ext_vector_type(8))) short;
using f32x4  = __attribute__((ext_vector_type(4))) float;

__device__ __forceinline__ unsigned short f2bf(float f) {
    union { float f; unsigned u; } v; v.f = f;
    unsigned r = v.u + 0x7fffu + ((v.u >> 16) & 1u);
    return (unsigned short)(r >> 16);
}
__device__ __forceinline__ unsigned pack2(float a, float b) {
    return (unsigned)f2bf(a) | ((unsigned)f2bf(b) << 16);
}
__device__ __forceinline__ float bflo(unsigned u) {
    union { unsigned u; float f; } v; v.u = u << 16; return v.f;
}
__device__ __forceinline__ float bfhi(unsigned u) {
    union { unsigned u; float f; } v; v.u = u & 0xffff0000u; return v.f;
}
// quad-of-4 butterfly sum via DPP quad_perm (VALU pipe, not ds_swizzle/LDS).
__device__ __forceinline__ float qsum4(float s) {
    union { float f; int i; } u, t;
    u.f = s;
    t.i = __builtin_amdgcn_update_dpp(0, u.i, 0xB1, 0xF, 0xF, true); // xor 1
    u.f += t.f;
    t.i = __builtin_amdgcn_update_dpp(0, u.i, 0x4E, 0xF, 0xF, true); // xor 2
    u.f += t.f;
    return u.f;
}

// ======================= Phase 1: QKV GEMM tile =============================
// t in [0,882): mt = t%98 (64-pixel strip), nt = t/98 (64 of 576 out ch).
__global__ __launch_bounds__(256) void k_p1(
    const float* __restrict__ x, const float* __restrict__ wq,
    const float* __restrict__ wk, const float* __restrict__ wv,
    unsigned short* __restrict__ qkv)
{
    extern __shared__ char smem[];
    unsigned short* As  = (unsigned short*)smem;     // 64 x 200 ushorts
    unsigned short* Bs  = As + 64 * 200;
    unsigned*       Asw = (unsigned*)smem;           // dword view, row stride 100
    unsigned*       Bsw = (unsigned*)(smem + 25600);

    const int tid = threadIdx.x;
    const int lane = tid & 63, wave = tid >> 6;
    const int l15  = lane & 15, quad = lane >> 4;
    const int wm   = (wave & 1) * 32, wn = (wave >> 1) * 32;

    const int t = blockIdx.x;
    const int mt = t % 98, nt = t / 98;
    const int m0 = mt * 64, n0 = nt * 64;
    const float* Wp = (nt < 3) ? (wq + (size_t)n0 * CIN)
                    : (nt < 6) ? (wk + (size_t)(n0 - 192) * CIN)
                               : (wv + (size_t)(n0 - 384) * CIN);

    #pragma unroll
    for (int i = 0; i < 6; ++i) {
        int u = tid + 256 * i;
        int pq = u & 15, c2 = u >> 4;            // pq: p-quad 0..15, c2: 0..95
        int pp = m0 + pq * 4;
        int bb = (pp >= HW) ? 1 : 0;
        const float* src = x + ((size_t)(bb * CIN + c2 * 2)) * HW + (pp - bb * HW);
        float4 f0 = *(const float4*)src;          // c = c2*2,   p..p+3
        float4 f1 = *(const float4*)(src + HW);   // c = c2*2+1, p..p+3
        Asw[(pq * 4 + 0) * 100 + c2] = pack2(f0.x, f1.x);
        Asw[(pq * 4 + 1) * 100 + c2] = pack2(f0.y, f1.y);
        Asw[(pq * 4 + 2) * 100 + c2] = pack2(f0.z, f1.z);
        Asw[(pq * 4 + 3) * 100 + c2] = pack2(f0.w, f1.w);
    }
    {
        int o = tid >> 2, c4 = tid & 3;
        #pragma unroll
        for (int i = 0; i < 12; ++i) {
            int cq = c4 + 4 * i;                 // 0..47
            float4 w = *(const float4*)(Wp + (size_t)o * CIN + cq * 4);
            uint2 d; d.x = pack2(w.x, w.y); d.y = pack2(w.z, w.w);
            *(uint2*)(Bsw + o * 100 + cq * 2) = d;
        }
    }
    __syncthreads();

    f32x4 acc[2][2] = {};
    const unsigned short* pa0 = As + (wm + l15) * 200 + quad * 8;
    const unsigned short* pb0 = Bs + (wn + l15) * 200 + quad * 8;
    #pragma unroll
    for (int s = 0; s < 6; ++s) {
        short8 a0 = *(const short8*)(pa0 + s * 32);
        short8 a1 = *(const short8*)(pa0 + 16 * 200 + s * 32);
        short8 b0 = *(const short8*)(pb0 + s * 32);
        short8 b1 = *(const short8*)(pb0 + 16 * 200 + s * 32);
        acc[0][0] = __builtin_amdgcn_mfma_f32_16x16x32_bf16(a0, b0, acc[0][0], 0, 0, 0);
        acc[0][1] = __builtin_amdgcn_mfma_f32_16x16x32_bf16(a0, b1, acc[0][1], 0, 0, 0);
        acc[1][0] = __builtin_amdgcn_mfma_f32_16x16x32_bf16(a1, b0, acc[1][0], 0, 0, 0);
        acc[1][1] = __builtin_amdgcn_mfma_f32_16x16x32_bf16(a1, b1, acc[1][1], 0, 0, 0);
    }

    const int gm = m0 + wm + quad * 4;   // global pixel row
    const int gn = n0 + wn + l15;        // output channel (0..575)
    #pragma unroll
    for (int ti = 0; ti < 2; ++ti)
        #pragma unroll
        for (int tj = 0; tj < 2; ++tj)
            #pragma unroll
            for (int rr = 0; rr < 4; ++rr)
                qkv[(size_t)(gm + ti * 16 + rr) * QKVLD + (gn + tj * 16)] =
                    f2bf(acc[ti][tj][rr]);
}

// ======================= Phase 2: windowed attention ========================
// t in [0,588): 49 8x8-pixel tiles x 12 (b,h). 4 threads/pixel (d split 4x8).
// K and V staged as bf16 in LDS; unpack to fp32 after the LDS read.
__global__ __launch_bounds__(256) void k_p2(
    const unsigned short* __restrict__ qkv, const float* __restrict__ pos,
    unsigned short* __restrict__ oact)
{
    extern __shared__ char smem[];
    unsigned short* kbuf = (unsigned short*)smem;   // [196 px][32 ch] stride 40
    unsigned short* vbuf = kbuf + 196 * KVSTR;

    const int tid = threadIdx.x;
    const int t = blockIdx.x;
    const int tz = t / 49, r49 = t - tz * 49;
    const int ty = r49 / 7, tx = r49 - ty * 7;
    const int bq = tz / 6, h = tz - bq * 6;
    const int y0 = ty * 8 - 3, x0 = tx * 8 - 3;

    const int sub = tid & 3, pix = tid >> 2;
    const int py = pix >> 3, px = pix & 7;
    const int y = ty * 8 + py, xx = tx * 8 + px;
    const int p = y * WIMG + xx;

    // R8d: issue Q + pos loads before staging so HBM latency overlaps the stores
    uint4 qv = *(const uint4*)(qkv + (size_t)(bq * HW + p) * QKVLD + h * 32 + sub * 8);
    float posr[13];
    #pragma unroll
    for (int i = 0; i < 13; ++i) posr[i] = pos[i];

    // unified K+V staging: 1568 uint4 units = 196 px * (4 k + 4 v), raw bf16
    #pragma unroll
    for (int i = 0; i < 7; ++i) {
        int u = tid + 256 * i;
        if (u < 1568) {
            int pp = u >> 3, uu = u & 7;
            int part = uu >> 2, sub8 = uu & 3;       // part 0=k, 1=v
            int ppy = pp / 14, ppx = pp - ppy * 14;
            int gy = y0 + ppy, gx = x0 + ppx;
            uint4 rv = make_uint4(0u, 0u, 0u, 0u);
            if ((unsigned)gy < 56u && (unsigned)gx < 56u)
                rv = *(const uint4*)(qkv +
                    (size_t)(bq * HW + gy * WIMG + gx) * QKVLD +
                    192 + part * 192 + h * 32 + sub8 * 8);
            *(uint4*)((part ? vbuf : kbuf) + pp * KVSTR + sub8 * 8) = rv;
        }
    }
    __syncthreads();

    float q0=bflo(qv.x), q1=bfhi(qv.x), q2=bflo(qv.y), q3=bfhi(qv.y);
    float q4=bflo(qv.z), q5=bfhi(qv.z), q6=bflo(qv.w), q7=bfhi(qv.w);

    float logits[49];
    #pragma unroll
    for (int kk = 0; kk < 49; ++kk) {
        const int ky = kk / 7, kx = kk % 7;
        const int pp = (py + ky) * 14 + (px + kx);
        uint4 kv = *(const uint4*)(kbuf + pp * KVSTR + sub * 8);
        float s = 0.f;
        s = fmaf(q0, bflo(kv.x), s); s = fmaf(q1, bfhi(kv.x), s);
        s = fmaf(q2, bflo(kv.y), s); s = fmaf(q3, bfhi(kv.y), s);
        s = fmaf(q4, bflo(kv.z), s); s = fmaf(q5, bfhi(kv.z), s);
        s = fmaf(q6, bflo(kv.w), s); s = fmaf(q7, bfhi(kv.w), s);
        logits[kk] = qsum4(s) + posr[ky + kx];   // R8b: DPP reduce (VALU pipe)
    }

    float m = logits[0];
    #pragma unroll
    for (int kk = 1; kk < 49; ++kk) m = fmaxf(m, logits[kk]);
    float sum = 0.f;
    #pragma unroll
    for (int kk = 0; kk < 49; ++kk) {
        logits[kk] = __expf(logits[kk] - m);
        sum += logits[kk];
    }

    float a0=0,a1=0,a2=0,a3=0,a4=0,a5=0,a6=0,a7=0;
    #pragma unroll
    for (int kk = 0; kk < 49; ++kk) {
        const int ky = kk / 7, kx = kk % 7;
        const int pp = (py + ky) * 14 + (px + kx);
        uint4 vv = *(const uint4*)(vbuf + pp * KVSTR + sub * 8);
        const float pw = logits[kk];             // R8c: inv deferred to epilogue
        a0 = fmaf(pw, bflo(vv.x), a0); a1 = fmaf(pw, bfhi(vv.x), a1);
        a2 = fmaf(pw, bflo(vv.y), a2); a3 = fmaf(pw, bfhi(vv.y), a3);
        a4 = fmaf(pw, bflo(vv.z), a4); a5 = fmaf(pw, bfhi(vv.z), a5);
        a6 = fmaf(pw, bflo(vv.w), a6); a7 = fmaf(pw, bfhi(vv.w), a7);
    }
    const float inv = 1.f / sum;
    a0 *= inv; a1 *= inv; a2 *= inv; a3 *= inv;
    a4 *= inv; a5 *= inv; a6 *= inv; a7 *= inv;

    ushort4 h0, h1;
    h0.x = f2bf(a0); h0.y = f2bf(a1); h0.z = f2bf(a2); h0.w = f2bf(a3);
    h1.x = f2bf(a4); h1.y = f2bf(a5); h1.z = f2bf(a6); h1.w = f2bf(a7);
    unsigned short* ob = oact + (size_t)(bq * HW + p) * CIN + h * 32 + sub * 8;
    *(ushort4*)ob       = h0;
    *(ushort4*)(ob + 4) = h1;
}

// ======================= Phase 3: projection tile ===========================
// t in [0,294): mt = t%3 (64 out ch), pt = t/3 (64-pixel strip).
__global__ __launch_bounds__(256) void k_p3(
    const float* __restrict__ wproj, const unsigned short* __restrict__ oact,
    float* __restrict__ out)
{
    extern __shared__ char smem[];
    unsigned short* As  = (unsigned short*)smem;
    unsigned short* Bs  = As + 64 * 200;
    unsigned*       Asw = (unsigned*)smem;

    const int tid = threadIdx.x;
    const int lane = tid & 63, wave = tid >> 6;
    const int l15  = lane & 15, quad = lane >> 4;
    const int wm   = (wave & 1) * 32, wn = (wave >> 1) * 32;

    const int t = blockIdx.x;
    const int mt = t % 3, pt = t / 3;
    {
        int o = tid >> 2, c4 = tid & 3;
        #pragma unroll
        for (int i = 0; i < 12; ++i) {
            int cq = c4 + 4 * i;
            float4 w = *(const float4*)(wproj + (size_t)(mt * 64 + o) * CIN + cq * 4);
            uint2 d; d.x = pack2(w.x, w.y); d.y = pack2(w.z, w.w);
            *(uint2*)(Asw + o * 100 + cq * 2) = d;
        }
    }
    {
        int rw = tid >> 2, s4 = tid & 3;
        #pragma unroll
        for (int i = 0; i < 6; ++i) {
            int seg = s4 + 4 * i;               // 0..23
            uint4 dv = *(const uint4*)(oact + (size_t)(pt * 64 + rw) * CIN + seg * 8);
            *(uint4*)(Bs + rw * 200 + seg * 8) = dv;
        }
    }
    __syncthreads();

    f32x4 acc[2][2] = {};
    const unsigned short* pa0 = As + (wm + l15) * 200 + quad * 8;
    const unsigned short* pb0 = Bs + (wn + l15) * 200 + quad * 8;
    #pragma unroll
    for (int s = 0; s < 6; ++s) {
        short8 a0 = *(const short8*)(pa0 + s * 32);
        short8 a1 = *(const short8*)(pa0 + 16 * 200 + s * 32);
        short8 b0 = *(const short8*)(pb0 + s * 32);
        short8 b1 = *(const short8*)(pb0 + 16 * 200 + s * 32);
        acc[0][0] = __builtin_amdgcn_mfma_f32_16x16x32_bf16(a0, b0, acc[0][0], 0, 0, 0);
        acc[0][1] = __builtin_amdgcn_mfma_f32_16x16x32_bf16(a0, b1, acc[0][1], 0, 0, 0);
        acc[1][0] = __builtin_amdgcn_mfma_f32_16x16x32_bf16(a1, b0, acc[1][0], 0, 0, 0);
        acc[1][1] = __builtin_amdgcn_mfma_f32_16x16x32_bf16(a1, b1, acc[1][1], 0, 0, 0);
    }

    const int bb = (pt * 64 >= HW) ? 1 : 0;
    const int pl = pt * 64 - bb * HW + wn + l15;      // col = pixel within batch
    const int go = mt * 64 + wm + quad * 4;           // row = output channel
    float* Yb = out + (size_t)bb * (CIN * HW);
    #pragma unroll
    for (int ti = 0; ti < 2; ++ti)
        #pragma unroll
        for (int tj = 0; tj < 2; ++tj)
            #pragma unroll
            for (int rr = 0; rr < 4; ++rr)
                Yb[(size_t)(go + ti * 16 + rr) * HW + pl + tj * 16] = acc[ti][tj][rr];
}

// ---------------------------------------------------------------------------
extern "C" void kernel_launch(void* const* d_in, const int* in_sizes, int n_in,
                              void* d_out, int out_size, void* d_ws, size_t ws_size,
                              hipStream_t stream)
{
    const float* x     = (const float*)d_in[0];
    const float* wq    = (const float*)d_in[1];
    const float* wk    = (const float*)d_in[2];
    const float* wv    = (const float*)d_in[3];
    const float* pos   = (const float*)d_in[4];
    const float* wproj = (const float*)d_in[5];

    char* ws = (char*)d_ws;
    unsigned short* qkvp  = (unsigned short*)ws;
    unsigned short* oactp = (unsigned short*)(ws + 7225344);
    float*          outp  = (float*)d_out;

    k_p1<<<dim3(882), dim3(256), SMEM_P1, stream>>>(x, wq, wk, wv, qkvp);
    k_p2<<<dim3(588), dim3(256), SMEM_P2, stream>>>(qkvp, pos, oactp);
    k_p3<<<dim3(294), dim3(256), SMEM_P1, stream>>>(wproj, oactp, outp);
}

// Round 4
// 105.580 us; speedup vs baseline: 1.2235x; 1.0780x over previous
//
#include <hip/hip_runtime.h>

// SASA plain 3-kernel pipeline, R9: R6 trust-region center + two proven p2 micro-opts.
// B=2, CIN=192, HW=3136, 6 heads x d=32, 7x7 window.
// Cost model: dur_us = kernels (~16us) + ~95us harness ws-poison (2x256MiB fills
// @~43us, HBM-bound -> fill time is the container-health gauge).
// History: R6=110.2 (fills 43.2) | R7 bf16-LDS p2 =129.2 (fills 43.1, partly real
// regression) | R8 bf16-LDS+micro =113.8 (fills 42.7 -> ~4us real p2 regression).
// Conclusion: bf16 LDS p2 regresses despite fewer LDS ops (quarter-wave bank
// imbalance 3:2 on windowed b128 reads + 16 unpack VALU/kk). REVERTED to fp32 LDS.
// R9 keeps only the two strict reductions validated in R8:
//  (a) logit quad-reduce via DPP quad_perm (VALU pipe) instead of __shfl_xor
//      (ds_swizzle on the bottleneck LDS pipe): -98 LDS ops/wave in QK loop.
//  (b) softmax 1/sum deferred to the 8 output accumulators (-41 VALU/thread).
//
// ws layout (bytes):
//   QKV  [6272][576] bf16 @ 0        q ch 0-191 | k 192-383 | v 384-575
//   OACT [6272][192] bf16 @ 7225344  attention out = proj B-operand

#define HW    3136
#define WIMG  56
#define CIN   192
#define QKVLD 576
#define SMEM_BYTES 53312

using short8 = __attribute__((ext_vector_type(8))) short;
using f32x4  = __attribute__((ext_vector_type(4))) float;

__device__ __forceinline__ unsigned short f2bf(float f) {
    union { float f; unsigned u; } v; v.f = f;
    unsigned r = v.u + 0x7fffu + ((v.u >> 16) & 1u);
    return (unsigned short)(r >> 16);
}
__device__ __forceinline__ unsigned pack2(float a, float b) {
    return (unsigned)f2bf(a) | ((unsigned)f2bf(b) << 16);
}
__device__ __forceinline__ float bflo(unsigned u) {
    union { unsigned u; float f; } v; v.u = u << 16; return v.f;
}
__device__ __forceinline__ float bfhi(unsigned u) {
    union { unsigned u; float f; } v; v.u = u & 0xffff0000u; return v.f;
}
// quad-of-4 butterfly sum via DPP quad_perm (VALU pipe, not ds_swizzle/LDS).
// Functionally validated in R8 (passed, absmax identical to shfl version).
__device__ __forceinline__ float qsum4(float s) {
    union { float f; int i; } u, t;
    u.f = s;
    t.i = __builtin_amdgcn_update_dpp(0, u.i, 0xB1, 0xF, 0xF, true); // xor 1
    u.f += t.f;
    t.i = __builtin_amdgcn_update_dpp(0, u.i, 0x4E, 0xF, 0xF, true); // xor 2
    u.f += t.f;
    return u.f;
}

// ======================= Phase 1: QKV GEMM tile =============================
// t in [0,882): mt = t%98 (64-pixel strip over b,p), nt = t/98 (64 of 576 out ch).
// A: transpose x[b][c][p] fp32 -> As[p][c] bf16 in staging. B: W rows -> bf16.
__global__ __launch_bounds__(256) void k_p1(
    const float* __restrict__ x, const float* __restrict__ wq,
    const float* __restrict__ wk, const float* __restrict__ wv,
    unsigned short* __restrict__ qkv)
{
    extern __shared__ char smem[];
    unsigned short* As  = (unsigned short*)smem;     // 64 x 200 ushorts
    unsigned short* Bs  = As + 64 * 200;
    unsigned*       Asw = (unsigned*)smem;           // dword view, row stride 100
    unsigned*       Bsw = (unsigned*)(smem + 25600);

    const int tid = threadIdx.x;
    const int lane = tid & 63, wave = tid >> 6;
    const int l15  = lane & 15, quad = lane >> 4;
    const int wm   = (wave & 1) * 32, wn = (wave >> 1) * 32;

    const int t = blockIdx.x;
    const int mt = t % 98, nt = t / 98;
    const int m0 = mt * 64, n0 = nt * 64;
    const float* Wp = (nt < 3) ? (wq + (size_t)n0 * CIN)
                    : (nt < 6) ? (wk + (size_t)(n0 - 192) * CIN)
                               : (wv + (size_t)(n0 - 384) * CIN);

    #pragma unroll
    for (int i = 0; i < 6; ++i) {
        int u = tid + 256 * i;
        int pq = u & 15, c2 = u >> 4;            // pq: p-quad 0..15, c2: 0..95
        int pp = m0 + pq * 4;
        int bb = (pp >= HW) ? 1 : 0;
        const float* src = x + ((size_t)(bb * CIN + c2 * 2)) * HW + (pp - bb * HW);
        float4 f0 = *(const float4*)src;          // c = c2*2,   p..p+3
        float4 f1 = *(const float4*)(src + HW);   // c = c2*2+1, p..p+3
        Asw[(pq * 4 + 0) * 100 + c2] = pack2(f0.x, f1.x);
        Asw[(pq * 4 + 1) * 100 + c2] = pack2(f0.y, f1.y);
        Asw[(pq * 4 + 2) * 100 + c2] = pack2(f0.z, f1.z);
        Asw[(pq * 4 + 3) * 100 + c2] = pack2(f0.w, f1.w);
    }
    {
        int o = tid >> 2, c4 = tid & 3;
        #pragma unroll
        for (int i = 0; i < 12; ++i) {
            int cq = c4 + 4 * i;                 // 0..47
            float4 w = *(const float4*)(Wp + (size_t)o * CIN + cq * 4);
            uint2 d; d.x = pack2(w.x, w.y); d.y = pack2(w.z, w.w);
            *(uint2*)(Bsw + o * 100 + cq * 2) = d;
        }
    }
    __syncthreads();

    f32x4 acc[2][2] = {};
    const unsigned short* pa0 = As + (wm + l15) * 200 + quad * 8;
    const unsigned short* pb0 = Bs + (wn + l15) * 200 + quad * 8;
    #pragma unroll
    for (int s = 0; s < 6; ++s) {
        short8 a0 = *(const short8*)(pa0 + s * 32);
        short8 a1 = *(const short8*)(pa0 + 16 * 200 + s * 32);
        short8 b0 = *(const short8*)(pb0 + s * 32);
        short8 b1 = *(const short8*)(pb0 + 16 * 200 + s * 32);
        acc[0][0] = __builtin_amdgcn_mfma_f32_16x16x32_bf16(a0, b0, acc[0][0], 0, 0, 0);
        acc[0][1] = __builtin_amdgcn_mfma_f32_16x16x32_bf16(a0, b1, acc[0][1], 0, 0, 0);
        acc[1][0] = __builtin_amdgcn_mfma_f32_16x16x32_bf16(a1, b0, acc[1][0], 0, 0, 0);
        acc[1][1] = __builtin_amdgcn_mfma_f32_16x16x32_bf16(a1, b1, acc[1][1], 0, 0, 0);
    }

    const int gm = m0 + wm + quad * 4;   // global pixel row
    const int gn = n0 + wn + l15;        // output channel (0..575)
    #pragma unroll
    for (int ti = 0; ti < 2; ++ti)
        #pragma unroll
        for (int tj = 0; tj < 2; ++tj)
            #pragma unroll
            for (int rr = 0; rr < 4; ++rr)
                qkv[(size_t)(gm + ti * 16 + rr) * QKVLD + (gn + tj * 16)] =
                    f2bf(acc[ti][tj][rr]);
}

// ======================= Phase 2: windowed attention ========================
// t in [0,588): 49 8x8-pixel tiles x 12 (b,h). 4 threads/pixel (d split 4x8).
// K and V staged bf16->fp32 into LDS in one unified loop (R6 layout, stride 34).
__global__ __launch_bounds__(256) void k_p2(
    const unsigned short* __restrict__ qkv, const float* __restrict__ pos,
    unsigned short* __restrict__ oact)
{
    extern __shared__ char smem[];
    float* kbuf = (float*)smem;          // [196 px][32 ch] stride 34 floats
    float* vbuf = kbuf + 6664;

    const int tid = threadIdx.x;
    const int t = blockIdx.x;
    const int tz = t / 49, r49 = t - tz * 49;
    const int ty = r49 / 7, tx = r49 - ty * 7;
    const int bq = tz / 6, h = tz - bq * 6;
    const int y0 = ty * 8 - 3, x0 = tx * 8 - 3;

    // unified K+V staging: 1568 uint4 units = 196 px * (4 k + 4 v)
    #pragma unroll
    for (int i = 0; i < 7; ++i) {
        int u = tid + 256 * i;
        if (u < 1568) {
            int pp = u >> 3, uu = u & 7;
            int part = uu >> 2, sub8 = uu & 3;       // part 0=k, 1=v
            int py = pp / 14, px = pp - py * 14;
            int gy = y0 + py, gx = x0 + px;
            float f0=0,f1=0,f2=0,f3=0,f4=0,f5=0,f6=0,f7=0;
            if ((unsigned)gy < 56u && (unsigned)gx < 56u) {
                uint4 rv = *(const uint4*)(qkv +
                    (size_t)(bq * HW + gy * WIMG + gx) * QKVLD +
                    192 + part * 192 + h * 32 + sub8 * 8);
                f0=bflo(rv.x); f1=bfhi(rv.x); f2=bflo(rv.y); f3=bfhi(rv.y);
                f4=bflo(rv.z); f5=bfhi(rv.z); f6=bflo(rv.w); f7=bfhi(rv.w);
            }
            float* dst = (part ? vbuf : kbuf) + pp * 34 + sub8 * 8;
            *(float2*)(dst + 0) = make_float2(f0, f1);
            *(float2*)(dst + 2) = make_float2(f2, f3);
            *(float2*)(dst + 4) = make_float2(f4, f5);
            *(float2*)(dst + 6) = make_float2(f6, f7);
        }
    }
    __syncthreads();

    const int sub = tid & 3, pix = tid >> 2;
    const int py = pix >> 3, px = pix & 7;
    const int y = ty * 8 + py, xx = tx * 8 + px;
    const int p = y * WIMG + xx;

    uint4 qv = *(const uint4*)(qkv + (size_t)(bq * HW + p) * QKVLD + h * 32 + sub * 8);
    float q0=bflo(qv.x), q1=bfhi(qv.x), q2=bflo(qv.y), q3=bfhi(qv.y);
    float q4=bflo(qv.z), q5=bfhi(qv.z), q6=bflo(qv.w), q7=bfhi(qv.w);

    float posr[13];
    #pragma unroll
    for (int i = 0; i < 13; ++i) posr[i] = pos[i];

    float logits[49];
    #pragma unroll
    for (int kk = 0; kk < 49; ++kk) {
        const int ky = kk / 7, kx = kk % 7;
        const int pp = (py + ky) * 14 + (px + kx);
        const float2* kp = (const float2*)(kbuf + pp * 34 + sub * 8);
        float2 k0 = kp[0], k1 = kp[1], k2 = kp[2], k3 = kp[3];
        float s = 0.f;
        s = fmaf(q0, k0.x, s); s = fmaf(q1, k0.y, s);
        s = fmaf(q2, k1.x, s); s = fmaf(q3, k1.y, s);
        s = fmaf(q4, k2.x, s); s = fmaf(q5, k2.y, s);
        s = fmaf(q6, k3.x, s); s = fmaf(q7, k3.y, s);
        logits[kk] = qsum4(s) + posr[ky + kx];   // R9a: DPP reduce (VALU pipe)
    }

    float m = logits[0];
    #pragma unroll
    for (int kk = 1; kk < 49; ++kk) m = fmaxf(m, logits[kk]);
    float sum = 0.f;
    #pragma unroll
    for (int kk = 0; kk < 49; ++kk) {
        logits[kk] = __expf(logits[kk] - m);
        sum += logits[kk];
    }

    float a0=0,a1=0,a2=0,a3=0,a4=0,a5=0,a6=0,a7=0;
    #pragma unroll
    for (int kk = 0; kk < 49; ++kk) {
        const int ky = kk / 7, kx = kk % 7;
        const int pp = (py + ky) * 14 + (px + kx);
        const float2* vp = (const float2*)(vbuf + pp * 34 + sub * 8);
        float2 v0 = vp[0], v1 = vp[1], v2 = vp[2], v3 = vp[3];
        const float pw = logits[kk];             // R9b: inv deferred to epilogue
        a0 = fmaf(pw, v0.x, a0); a1 = fmaf(pw, v0.y, a1);
        a2 = fmaf(pw, v1.x, a2); a3 = fmaf(pw, v1.y, a3);
        a4 = fmaf(pw, v2.x, a4); a5 = fmaf(pw, v2.y, a5);
        a6 = fmaf(pw, v3.x, a6); a7 = fmaf(pw, v3.y, a7);
    }
    const float inv = 1.f / sum;
    a0 *= inv; a1 *= inv; a2 *= inv; a3 *= inv;
    a4 *= inv; a5 *= inv; a6 *= inv; a7 *= inv;

    ushort4 h0, h1;
    h0.x = f2bf(a0); h0.y = f2bf(a1); h0.z = f2bf(a2); h0.w = f2bf(a3);
    h1.x = f2bf(a4); h1.y = f2bf(a5); h1.z = f2bf(a6); h1.w = f2bf(a7);
    unsigned short* ob = oact + (size_t)(bq * HW + p) * CIN + h * 32 + sub * 8;
    *(ushort4*)ob       = h0;
    *(ushort4*)(ob + 4) = h1;
}

// ======================= Phase 3: projection tile ===========================
// t in [0,294): mt = t%3 (64 out ch), pt = t/3 (64-pixel strip).
__global__ __launch_bounds__(256) void k_p3(
    const float* __restrict__ wproj, const unsigned short* __restrict__ oact,
    float* __restrict__ out)
{
    extern __shared__ char smem[];
    unsigned short* As  = (unsigned short*)smem;
    unsigned short* Bs  = As + 64 * 200;
    unsigned*       Asw = (unsigned*)smem;

    const int tid = threadIdx.x;
    const int lane = tid & 63, wave = tid >> 6;
    const int l15  = lane & 15, quad = lane >> 4;
    const int wm   = (wave & 1) * 32, wn = (wave >> 1) * 32;

    const int t = blockIdx.x;
    const int mt = t % 3, pt = t / 3;
    {
        int o = tid >> 2, c4 = tid & 3;
        #pragma unroll
        for (int i = 0; i < 12; ++i) {
            int cq = c4 + 4 * i;
            float4 w = *(const float4*)(wproj + (size_t)(mt * 64 + o) * CIN + cq * 4);
            uint2 d; d.x = pack2(w.x, w.y); d.y = pack2(w.z, w.w);
            *(uint2*)(Asw + o * 100 + cq * 2) = d;
        }
    }
    {
        int rw = tid >> 2, s4 = tid & 3;
        #pragma unroll
        for (int i = 0; i < 6; ++i) {
            int seg = s4 + 4 * i;               // 0..23
            uint4 dv = *(const uint4*)(oact + (size_t)(pt * 64 + rw) * CIN + seg * 8);
            *(uint4*)(Bs + rw * 200 + seg * 8) = dv;
        }
    }
    __syncthreads();

    f32x4 acc[2][2] = {};
    const unsigned short* pa0 = As + (wm + l15) * 200 + quad * 8;
    const unsigned short* pb0 = Bs + (wn + l15) * 200 + quad * 8;
    #pragma unroll
    for (int s = 0; s < 6; ++s) {
        short8 a0 = *(const short8*)(pa0 + s * 32);
        short8 a1 = *(const short8*)(pa0 + 16 * 200 + s * 32);
        short8 b0 = *(const short8*)(pb0 + s * 32);
        short8 b1 = *(const short8*)(pb0 + 16 * 200 + s * 32);
        acc[0][0] = __builtin_amdgcn_mfma_f32_16x16x32_bf16(a0, b0, acc[0][0], 0, 0, 0);
        acc[0][1] = __builtin_amdgcn_mfma_f32_16x16x32_bf16(a0, b1, acc[0][1], 0, 0, 0);
        acc[1][0] = __builtin_amdgcn_mfma_f32_16x16x32_bf16(a1, b0, acc[1][0], 0, 0, 0);
        acc[1][1] = __builtin_amdgcn_mfma_f32_16x16x32_bf16(a1, b1, acc[1][1], 0, 0, 0);
    }

    const int bb = (pt * 64 >= HW) ? 1 : 0;
    const int pl = pt * 64 - bb * HW + wn + l15;      // col = pixel within batch
    const int go = mt * 64 + wm + quad * 4;           // row = output channel
    float* Yb = out + (size_t)bb * (CIN * HW);
    #pragma unroll
    for (int ti = 0; ti < 2; ++ti)
        #pragma unroll
        for (int tj = 0; tj < 2; ++tj)
            #pragma unroll
            for (int rr = 0; rr < 4; ++rr)
                Yb[(size_t)(go + ti * 16 + rr) * HW + pl + tj * 16] = acc[ti][tj][rr];
}

// ---------------------------------------------------------------------------
extern "C" void kernel_launch(void* const* d_in, const int* in_sizes, int n_in,
                              void* d_out, int out_size, void* d_ws, size_t ws_size,
                              hipStream_t stream)
{
    const float* x     = (const float*)d_in[0];
    const float* wq    = (const float*)d_in[1];
    const float* wk    = (const float*)d_in[2];
    const float* wv    = (const float*)d_in[3];
    const float* pos   = (const float*)d_in[4];
    const float* wproj = (const float*)d_in[5];

    char* ws = (char*)d_ws;
    unsigned short* qkvp  = (unsigned short*)ws;
    unsigned short* oactp = (unsigned short*)(ws + 7225344);
    float*          outp  = (float*)d_out;

    k_p1<<<dim3(882), dim3(256), SMEM_BYTES, stream>>>(x, wq, wk, wv, qkvp);
    k_p2<<<dim3(588), dim3(256), SMEM_BYTES, stream>>>(qkvp, pos, oactp);
    k_p3<<<dim3(294), dim3(256), SMEM_BYTES, stream>>>(wproj, oactp, outp);
}